// Round 4
// baseline (251.339 us; speedup 1.0000x reference)
//
#include <hip/hip_runtime.h>

typedef short short8 __attribute__((ext_vector_type(8)));
typedef float f32x4 __attribute__((ext_vector_type(4)));

#define H_ 384
#define W_ 384
#define C_ 32
#define F_ 32
#define HW_ 147456          // H_*W_
#define HP1F 385.0f         // (H+2*pad)-1 as float
#define NB 2                // pixel batches per wave

__device__ __forceinline__ unsigned short f2bf(float f) {
  unsigned int u = __float_as_uint(f);
  u += 0x7fffu + ((u >> 16) & 1u);   // RNE
  return (unsigned short)(u >> 16);
}

__global__ __launch_bounds__(256, 4) void deform_conv_kernel(
    const float* __restrict__ x, const float* __restrict__ off,
    const float* __restrict__ kern, const float* __restrict__ bias,
    float* __restrict__ out) {
  // Per-wave A-tile region: 16 rows x (288+8 pad) bf16 = 9472 B; 4 waves = 37,888 B.
  // First 9216 shorts double as B-pack staging before the pixel loop.
  // NOTE: each wave touches ONLY its own 16x296 slab in the main loop, so the
  // main loop needs NO __syncthreads — wave-internal DS ordering (in-order DS
  // pipe + compiler lgkmcnt waits on may-alias LDS) is sufficient.
  __shared__ short ldsA[4 * 16 * 296];

  const int tid = threadIdx.x;
  const int lane = tid & 63;
  const int wv = tid >> 6;

  // ---- stage packed B fragments (bf16, MFMA B-operand layout) through LDS ----
  short8 bfrag[2][9];
  {
    unsigned short* pk = (unsigned short*)ldsA;
    for (int e = tid; e < 1152; e += 256) {   // 2 f-tiles * 9 k-steps * 64 lanes
      const int ln = e & 63;
      const int kk = (e >> 6) % 9;
      const int nt = e / 576;
      const int f = nt * 16 + (ln & 15);
      const int q2 = ln >> 4;
      unsigned short rr[8];
#pragma unroll
      for (int i2 = 0; i2 < 8; ++i2) {
        const int c = q2 * 8 + i2;                     // contraction idx = kk*32 + c
        rr[i2] = f2bf(kern[(kk * 32 + c) * 32 + f]);
      }
      uint4 w;
      w.x = rr[0] | ((unsigned)rr[1] << 16);
      w.y = rr[2] | ((unsigned)rr[3] << 16);
      w.z = rr[4] | ((unsigned)rr[5] << 16);
      w.w = rr[6] | ((unsigned)rr[7] << 16);
      *(uint4*)&pk[e * 8] = w;
    }
    __syncthreads();
    const short8* bp = (const short8*)ldsA;
#pragma unroll
    for (int nt = 0; nt < 2; ++nt)
#pragma unroll
      for (int kk = 0; kk < 9; ++kk)
        bfrag[nt][kk] = bp[(nt * 9 + kk) * 64 + lane];
    __syncthreads();   // staging area becomes wave 0/1's A-slabs below
  }

  const float bias0 = bias[lane & 15];
  const float bias1 = bias[16 + (lane & 15)];

  const int q = lane >> 3;          // (pixel,tap) slot within wave, 0..7
  const int c0 = (lane & 7) * 4;    // c-quad
  const int mrow = lane & 15;       // MFMA A row
  const int qq = lane >> 4;         // MFMA quad

  short* aW = ldsA + wv * (16 * 296);

  // XCD-aware swizzle: physical block p lands on XCD p%8; give each XCD a
  // contiguous run of 288 logical blocks (96 contiguous image rows) so its
  // 4 MiB L2 holds the streaming reuse window (~2.4 MB) and the halo is
  // fetched by exactly one XCD. Bijection over [0,2304): blk=8q+r -> 288r+q.
  const int lb = (blockIdx.x & 7) * 288 + (blockIdx.x >> 3);

  for (int nb = 0; nb < NB; ++nb) {
    const int g = lb * (4 * NB) + nb * 4 + wv;           // wave-group index
    const int P0 = g << 4;                               // first of 16 pixels
    const int b = (P0 >= HW_) ? 1 : 0;
    const int rem = P0 - b * HW_;
    const int i = rem / W_;
    const int j0 = rem - i * W_;     // group never crosses a row (W%16==0)

    // ---- prefetch all 18 offset pairs for this batch: 18 independent loads
    // in flight before any gather chain starts ----
    float2 oreg[18];
#pragma unroll
    for (int it = 0; it < 18; ++it) {
      const int pair = it * 8 + q;        // encodes k*16 + m
      const int m = pair & 15;
      const int k = pair >> 4;
      oreg[it] = *(const float2*)(off + (((i * W_) + (j0 + m)) * 9 + k) * 2);
    }

    // ---- sampling: 144 (m,tap) pairs, 8 per wave-iteration ----
#pragma unroll 3
    for (int it = 0; it < 18; ++it) {
      const int pair = it * 8 + q;        // encodes k*16 + m
      const int m = pair & 15;
      const int k = pair >> 4;
      const int j = j0 + m;
      const float2 o = oreg[it];
      const int di = k / 3;
      const int dj = k - di * 3;
      float yf = (float)(i + di) + o.y;   // padded coords; o.y = y_off
      float xf = (float)(j + dj) + o.x;   // o.x = x_off
      yf = fminf(fmaxf(yf, 0.f), HP1F);
      xf = fminf(fmaxf(xf, 0.f), HP1F);
      const float y0f = floorf(yf);
      const float x0f = floorf(xf);
      const int y0 = (int)y0f;
      const int x0 = (int)x0f;

      float v0, v1, v2, v3;
      // Fast path: all 4 corners strictly inside the image (y0,x0 in [1,383]
      // => y1=y0+1, x1=x0+1 in [2,384], all 4 rows/cols are real data).
      // Wave-uniform branch via __all: ~94% of iterations (offsets ~N(0,1)).
      const int fast = ((unsigned)(y0 - 1) < 383u) & ((unsigned)(x0 - 1) < 383u);
      if (__all(fast)) {
        const float wy1 = yf - y0f;
        const float wy0 = (y0f + 1.0f) - yf;   // == (float)y1 - yf, y1=y0+1
        const float wx1 = xf - x0f;
        const float wx0 = (x0f + 1.0f) - xf;
        const float w00 = wy0 * wx0, w01 = wy0 * wx1;
        const float w10 = wy1 * wx0, w11 = wy1 * wx1;
        const int base00 = ((b * H_ + (y0 - 1)) * W_ + (x0 - 1)) * C_ + c0;
        // 4 unconditional, independent 16B gathers -> all in flight together
        const float4 p00 = *(const float4*)(x + base00);
        const float4 p01 = *(const float4*)(x + base00 + C_);
        const float4 p10 = *(const float4*)(x + base00 + W_ * C_);
        const float4 p11 = *(const float4*)(x + base00 + W_ * C_ + C_);
        v0 = w00 * p00.x + w01 * p01.x + w10 * p10.x + w11 * p11.x;
        v1 = w00 * p00.y + w01 * p01.y + w10 * p10.y + w11 * p11.y;
        v2 = w00 * p00.z + w01 * p01.z + w10 * p10.z + w11 * p11.z;
        v3 = w00 * p00.w + w01 * p01.w + w10 * p10.w + w11 * p11.w;
      } else {
        // Slow path: verbatim R0 logic (guarded loads, pad corners -> 0).
        const int y1 = min(y0 + 1, 385);
        const int x1 = min(x0 + 1, 385);
        const float wy1 = yf - y0f;
        const float wy0 = (float)y1 - yf;
        const float wx1 = xf - x0f;
        const float wx0 = (float)x1 - xf;
        const float w00 = wy0 * wx0, w01 = wy0 * wx1;
        const float w10 = wy1 * wx0, w11 = wy1 * wx1;

        const int yu0 = y0 - 1, xu0 = x0 - 1;
        const bool vy0 = (unsigned)yu0 < 384u, vy1 = (unsigned)(y1 - 1) < 384u;
        const bool vx0 = (unsigned)xu0 < 384u, vx1 = (unsigned)(x1 - 1) < 384u;
        const int base00 = ((b * H_ + yu0) * W_ + xu0) * C_ + c0;
        const int ddx = (x1 - x0) * C_;
        const int ddy = (y1 - y0) * (W_ * C_);
        float4 p00 = {0.f, 0.f, 0.f, 0.f}, p01 = {0.f, 0.f, 0.f, 0.f};
        float4 p10 = {0.f, 0.f, 0.f, 0.f}, p11 = {0.f, 0.f, 0.f, 0.f};
        if (vy0 && vx0) p00 = *(const float4*)(x + base00);
        if (vy0 && vx1) p01 = *(const float4*)(x + base00 + ddx);
        if (vy1 && vx0) p10 = *(const float4*)(x + base00 + ddy);
        if (vy1 && vx1) p11 = *(const float4*)(x + base00 + ddy + ddx);

        v0 = w00 * p00.x + w01 * p01.x + w10 * p10.x + w11 * p11.x;
        v1 = w00 * p00.y + w01 * p01.y + w10 * p10.y + w11 * p11.y;
        v2 = w00 * p00.z + w01 * p01.z + w10 * p10.z + w11 * p11.z;
        v3 = w00 * p00.w + w01 * p01.w + w10 * p10.w + w11 * p11.w;
      }

      uint2 pw;
      pw.x = f2bf(v0) | ((unsigned)f2bf(v1) << 16);
      pw.y = f2bf(v2) | ((unsigned)f2bf(v3) << 16);
      *(uint2*)&aW[m * 296 + k * 32 + c0] = pw;
    }
    // NO barrier: A-slab is wave-private; DS pipe is in-order per wave and the
    // compiler inserts lgkmcnt waits for the may-alias write->read below.

    // ---- contraction: [16 x 288] x [288 x 32] via 9x2 MFMAs ----
    f32x4 acc0 = {bias0, bias0, bias0, bias0};
    f32x4 acc1 = {bias1, bias1, bias1, bias1};
#pragma unroll
    for (int kk = 0; kk < 9; ++kk) {
      const short8 af = *(const short8*)(aW + mrow * 296 + kk * 32 + qq * 8);
      acc0 = __builtin_amdgcn_mfma_f32_16x16x32_bf16(af, bfrag[0][kk], acc0, 0, 0, 0);
      acc1 = __builtin_amdgcn_mfma_f32_16x16x32_bf16(af, bfrag[1][kk], acc1, 0, 0, 0);
    }

    // D layout: col = lane&15, row = qq*4 + reg
    float* op = out + (size_t)(P0 + qq * 4) * 32 + (lane & 15);
#pragma unroll
    for (int r = 0; r < 4; ++r) {
      op[r * 32] = acc0[r];
      op[r * 32 + 16] = acc1[r];
    }
    // NO barrier: next batch's writes to this wave's slab are ordered after
    // this wave's MFMA reads by the in-order per-wave DS pipe.
  }
}

extern "C" void kernel_launch(void* const* d_in, const int* in_sizes, int n_in,
                              void* d_out, int out_size, void* d_ws, size_t ws_size,
                              hipStream_t stream) {
  const float* x    = (const float*)d_in[0];
  const float* off  = (const float*)d_in[1];
  const float* kern = (const float*)d_in[2];
  const float* bias = (const float*)d_in[3];
  float* out = (float*)d_out;
  // 294912 pixels / (4 waves * 16 px * NB batches) = 2304 blocks
  deform_conv_kernel<<<dim3(2304), dim3(256), 0, stream>>>(x, off, kern, bias, out);
}

// Round 5
// 224.303 us; speedup vs baseline: 1.1205x; 1.1205x over previous
//
#include <hip/hip_runtime.h>

typedef short short8 __attribute__((ext_vector_type(8)));
typedef float f32x4 __attribute__((ext_vector_type(4)));

#define H_ 384
#define W_ 384
#define C_ 32
#define F_ 32
#define HW_ 147456          // H_*W_
#define HP1F 385.0f         // (H+2*pad)-1 as float
#define NB 2                // pixel batches per wave

__device__ __forceinline__ unsigned short f2bf(float f) {
  unsigned int u = __float_as_uint(f);
  u += 0x7fffu + ((u >> 16) & 1u);   // RNE
  return (unsigned short)(u >> 16);
}

__global__ __launch_bounds__(256, 4) void deform_conv_kernel(
    const float* __restrict__ x, const float* __restrict__ off,
    const float* __restrict__ kern, const float* __restrict__ bias,
    float* __restrict__ out) {
  // Per-wave A-tile region: 16 rows x (288+8 pad) bf16 = 9472 B; 4 waves = 37,888 B.
  // First 9216 shorts double as B-pack staging before the pixel loop.
  // Main loop has NO __syncthreads: each wave touches only its own 16x296
  // slab, so per-wave in-order DS + compiler lgkmcnt ordering suffices
  // (verified R3: absmax bit-identical with barriers removed).
  __shared__ short ldsA[4 * 16 * 296];

  const int tid = threadIdx.x;
  const int lane = tid & 63;
  const int wv = tid >> 6;

  // ---- stage packed B fragments (bf16, MFMA B-operand layout) through LDS ----
  short8 bfrag[2][9];
  {
    unsigned short* pk = (unsigned short*)ldsA;
    for (int e = tid; e < 1152; e += 256) {   // 2 f-tiles * 9 k-steps * 64 lanes
      const int ln = e & 63;
      const int kk = (e >> 6) % 9;
      const int nt = e / 576;
      const int f = nt * 16 + (ln & 15);
      const int q2 = ln >> 4;
      unsigned short rr[8];
#pragma unroll
      for (int i2 = 0; i2 < 8; ++i2) {
        const int c = q2 * 8 + i2;                     // contraction idx = kk*32 + c
        rr[i2] = f2bf(kern[(kk * 32 + c) * 32 + f]);
      }
      uint4 w;
      w.x = rr[0] | ((unsigned)rr[1] << 16);
      w.y = rr[2] | ((unsigned)rr[3] << 16);
      w.z = rr[4] | ((unsigned)rr[5] << 16);
      w.w = rr[6] | ((unsigned)rr[7] << 16);
      *(uint4*)&pk[e * 8] = w;
    }
    __syncthreads();
    const short8* bp = (const short8*)ldsA;
#pragma unroll
    for (int nt = 0; nt < 2; ++nt)
#pragma unroll
      for (int kk = 0; kk < 9; ++kk)
        bfrag[nt][kk] = bp[(nt * 9 + kk) * 64 + lane];
    __syncthreads();   // staging area becomes wave 0/1's A-slabs below
  }

  const float bias0 = bias[lane & 15];
  const float bias1 = bias[16 + (lane & 15)];

  const int q = lane >> 3;          // (pixel,tap) slot within wave, 0..7
  const int c0 = (lane & 7) * 4;    // c-quad
  const int mrow = lane & 15;       // MFMA A row
  const int qq = lane >> 4;         // MFMA quad

  short* aW = ldsA + wv * (16 * 296);

  // XCD-aware swizzle: physical block p lands on XCD p%8; give each XCD a
  // contiguous run of 288 logical blocks (96 contiguous image rows) so its
  // 4 MiB L2 holds the streaming reuse window (~2.4 MB) and the halo is
  // fetched by exactly one XCD. Bijection over [0,2304): blk=8q+r -> 288r+q.
  const int lb = (blockIdx.x & 7) * 288 + (blockIdx.x >> 3);

  for (int nb = 0; nb < NB; ++nb) {
    const int g = lb * (4 * NB) + nb * 4 + wv;           // wave-group index
    const int P0 = g << 4;                               // first of 16 pixels
    const int b = (P0 >= HW_) ? 1 : 0;
    const int rem = P0 - b * HW_;
    const int i = rem / W_;
    const int j0 = rem - i * W_;     // group never crosses a row (W%16==0)

    // ---- prefetch all 18 offset pairs for this batch. FULLY-UNROLLED
    // consumers below index oreg[] with constants only -> stays in VGPRs.
    // (R3 lesson: dynamic indexing spilled this to scratch: WRITE_SIZE 211 MB.)
    float2 oreg[18];
#pragma unroll
    for (int it = 0; it < 18; ++it) {
      const int pair = it * 8 + q;        // encodes k*16 + m
      const int m = pair & 15;
      const int k = pair >> 4;
      oreg[it] = *(const float2*)(off + (((i * W_) + (j0 + m)) * 9 + k) * 2);
    }

    // ---- sampling: 144 (m,tap) pairs, 8 per wave-iteration, FULL unroll ----
#pragma unroll
    for (int it = 0; it < 18; ++it) {
      const int pair = it * 8 + q;        // encodes k*16 + m
      const int m = pair & 15;
      const int k = pair >> 4;
      const int j = j0 + m;
      const float2 o = oreg[it];
      const int di = k / 3;
      const int dj = k - di * 3;
      float yf = (float)(i + di) + o.y;   // padded coords; o.y = y_off
      float xf = (float)(j + dj) + o.x;   // o.x = x_off
      yf = fminf(fmaxf(yf, 0.f), HP1F);
      xf = fminf(fmaxf(xf, 0.f), HP1F);
      const float y0f = floorf(yf);
      const float x0f = floorf(xf);
      const int y0 = (int)y0f;
      const int x0 = (int)x0f;

      float v0, v1, v2, v3;
      // Fast path: all 4 corners strictly inside the image (y0,x0 in [1,383]
      // => y1=y0+1, x1=x0+1 in [2,384], all 4 rows/cols are real data).
      // Wave-uniform branch via __all: ~94% of iterations (offsets ~N(0,1)).
      const int fast = ((unsigned)(y0 - 1) < 383u) & ((unsigned)(x0 - 1) < 383u);
      if (__all(fast)) {
        const float wy1 = yf - y0f;
        const float wy0 = (y0f + 1.0f) - yf;   // == (float)y1 - yf, y1=y0+1
        const float wx1 = xf - x0f;
        const float wx0 = (x0f + 1.0f) - xf;
        const float w00 = wy0 * wx0, w01 = wy0 * wx1;
        const float w10 = wy1 * wx0, w11 = wy1 * wx1;
        const int base00 = ((b * H_ + (y0 - 1)) * W_ + (x0 - 1)) * C_ + c0;
        // 4 unconditional, independent 16B gathers -> all in flight together
        const float4 p00 = *(const float4*)(x + base00);
        const float4 p01 = *(const float4*)(x + base00 + C_);
        const float4 p10 = *(const float4*)(x + base00 + W_ * C_);
        const float4 p11 = *(const float4*)(x + base00 + W_ * C_ + C_);
        v0 = w00 * p00.x + w01 * p01.x + w10 * p10.x + w11 * p11.x;
        v1 = w00 * p00.y + w01 * p01.y + w10 * p10.y + w11 * p11.y;
        v2 = w00 * p00.z + w01 * p01.z + w10 * p10.z + w11 * p11.z;
        v3 = w00 * p00.w + w01 * p01.w + w10 * p10.w + w11 * p11.w;
      } else {
        // Slow path: verbatim R0 logic (guarded loads, pad corners -> 0).
        const int y1 = min(y0 + 1, 385);
        const int x1 = min(x0 + 1, 385);
        const float wy1 = yf - y0f;
        const float wy0 = (float)y1 - yf;
        const float wx1 = xf - x0f;
        const float wx0 = (float)x1 - xf;
        const float w00 = wy0 * wx0, w01 = wy0 * wx1;
        const float w10 = wy1 * wx0, w11 = wy1 * wx1;

        const int yu0 = y0 - 1, xu0 = x0 - 1;
        const bool vy0 = (unsigned)yu0 < 384u, vy1 = (unsigned)(y1 - 1) < 384u;
        const bool vx0 = (unsigned)xu0 < 384u, vx1 = (unsigned)(x1 - 1) < 384u;
        const int base00 = ((b * H_ + yu0) * W_ + xu0) * C_ + c0;
        const int ddx = (x1 - x0) * C_;
        const int ddy = (y1 - y0) * (W_ * C_);
        float4 p00 = {0.f, 0.f, 0.f, 0.f}, p01 = {0.f, 0.f, 0.f, 0.f};
        float4 p10 = {0.f, 0.f, 0.f, 0.f}, p11 = {0.f, 0.f, 0.f, 0.f};
        if (vy0 && vx0) p00 = *(const float4*)(x + base00);
        if (vy0 && vx1) p01 = *(const float4*)(x + base00 + ddx);
        if (vy1 && vx0) p10 = *(const float4*)(x + base00 + ddy);
        if (vy1 && vx1) p11 = *(const float4*)(x + base00 + ddy + ddx);

        v0 = w00 * p00.x + w01 * p01.x + w10 * p10.x + w11 * p11.x;
        v1 = w00 * p00.y + w01 * p01.y + w10 * p10.y + w11 * p11.y;
        v2 = w00 * p00.z + w01 * p01.z + w10 * p10.z + w11 * p11.z;
        v3 = w00 * p00.w + w01 * p01.w + w10 * p10.w + w11 * p11.w;
      }

      uint2 pw;
      pw.x = f2bf(v0) | ((unsigned)f2bf(v1) << 16);
      pw.y = f2bf(v2) | ((unsigned)f2bf(v3) << 16);
      *(uint2*)&aW[m * 296 + k * 32 + c0] = pw;
    }
    // NO barrier: A-slab is wave-private; per-wave DS ordering suffices.

    // ---- contraction: [16 x 288] x [288 x 32] via 9x2 MFMAs ----
    f32x4 acc0 = {bias0, bias0, bias0, bias0};
    f32x4 acc1 = {bias1, bias1, bias1, bias1};
#pragma unroll
    for (int kk = 0; kk < 9; ++kk) {
      const short8 af = *(const short8*)(aW + mrow * 296 + kk * 32 + qq * 8);
      acc0 = __builtin_amdgcn_mfma_f32_16x16x32_bf16(af, bfrag[0][kk], acc0, 0, 0, 0);
      acc1 = __builtin_amdgcn_mfma_f32_16x16x32_bf16(af, bfrag[1][kk], acc1, 0, 0, 0);
    }

    // D layout: col = lane&15, row = qq*4 + reg
    float* op = out + (size_t)(P0 + qq * 4) * 32 + (lane & 15);
#pragma unroll
    for (int r = 0; r < 4; ++r) {
      op[r * 32] = acc0[r];
      op[r * 32 + 16] = acc1[r];
    }
    // NO barrier: next batch's writes to this wave's slab are ordered after
    // this wave's MFMA reads by the in-order per-wave DS pipe.
  }
}

extern "C" void kernel_launch(void* const* d_in, const int* in_sizes, int n_in,
                              void* d_out, int out_size, void* d_ws, size_t ws_size,
                              hipStream_t stream) {
  const float* x    = (const float*)d_in[0];
  const float* off  = (const float*)d_in[1];
  const float* kern = (const float*)d_in[2];
  const float* bias = (const float*)d_in[3];
  float* out = (float*)d_out;
  // 294912 pixels / (4 waves * 16 px * NB batches) = 2304 blocks
  deform_conv_kernel<<<dim3(2304), dim3(256), 0, stream>>>(x, off, kern, bias, out);
}

// Round 6
// 185.496 us; speedup vs baseline: 1.3550x; 1.2092x over previous
//
#include <hip/hip_runtime.h>

typedef short short8 __attribute__((ext_vector_type(8)));
typedef float f32x4 __attribute__((ext_vector_type(4)));

#define H_ 384
#define W_ 384
#define C_ 32
#define F_ 32
#define HW_ 147456          // H_*W_
#define HP1F 385.0f         // (H+2*pad)-1 as float
#define NB 2                // pixel batches per wave
#define SLAB_STRIDE 40      // 32 shorts data + 8 pad: bank(m)=(m*20)%32 -> 2-way-free b128

__device__ __forceinline__ unsigned short f2bf(float f) {
  unsigned int u = __float_as_uint(f);
  u += 0x7fffu + ((u >> 16) & 1u);   // RNE
  return (unsigned short)(u >> 16);
}

__global__ __launch_bounds__(256) void deform_conv_kernel(
    const float* __restrict__ x, const float* __restrict__ off,
    const float* __restrict__ kern, const float* __restrict__ bias,
    float* __restrict__ out) {
  // LDS: 9216 shorts (18.4 KB). Used once for B-fragment staging (with the
  // only two barriers in the kernel), then re-carved as 4 per-wave k-step
  // slabs of 2 x 16 x SLAB_STRIDE shorts (double-buffered single-tap tiles).
  // Main loop is barrier-free: slabs are wave-private, per-wave DS is
  // in-order (verified bit-exact in R3/R4).
  __shared__ short ldsA[9216];

  const int tid = threadIdx.x;
  const int lane = tid & 63;
  const int wv = tid >> 6;

  // ---- stage packed B fragments (bf16, MFMA B-operand layout) through LDS ----
  short8 bfrag[2][9];
  {
    unsigned short* pk = (unsigned short*)ldsA;
    for (int e = tid; e < 1152; e += 256) {   // 2 f-tiles * 9 k-steps * 64 lanes
      const int ln = e & 63;
      const int kk = (e >> 6) % 9;
      const int nt = e / 576;
      const int f = nt * 16 + (ln & 15);
      const int q2 = ln >> 4;
      unsigned short rr[8];
#pragma unroll
      for (int i2 = 0; i2 < 8; ++i2) {
        const int c = q2 * 8 + i2;                     // contraction idx = kk*32 + c
        rr[i2] = f2bf(kern[(kk * 32 + c) * 32 + f]);
      }
      uint4 w;
      w.x = rr[0] | ((unsigned)rr[1] << 16);
      w.y = rr[2] | ((unsigned)rr[3] << 16);
      w.z = rr[4] | ((unsigned)rr[5] << 16);
      w.w = rr[6] | ((unsigned)rr[7] << 16);
      *(uint4*)&pk[e * 8] = w;
    }
    __syncthreads();
    const short8* bp = (const short8*)ldsA;
#pragma unroll
    for (int nt = 0; nt < 2; ++nt)
#pragma unroll
      for (int kk = 0; kk < 9; ++kk)
        bfrag[nt][kk] = bp[(nt * 9 + kk) * 64 + lane];
    __syncthreads();   // staging area becomes the per-wave slabs below
  }

  const float bias0 = bias[lane & 15];
  const float bias1 = bias[16 + (lane & 15)];

  const int q = lane >> 3;          // (pixel,tap) slot within wave, 0..7
  const int c0 = (lane & 7) * 4;    // c-quad
  const int mrow = lane & 15;       // MFMA A row
  const int qq = lane >> 4;         // MFMA quad

  short* slab = ldsA + wv * (2 * 16 * SLAB_STRIDE);   // wave-private dbuf

  // XCD-aware swizzle: physical block p lands on XCD p%8; give each XCD a
  // contiguous run of 288 logical blocks (96 contiguous image rows) so its
  // 4 MiB L2 holds the streaming reuse window and the halo is fetched by
  // exactly one XCD. Bijection over [0,2304): blk=8q+r -> 288r+q.
  const int lb = (blockIdx.x & 7) * 288 + (blockIdx.x >> 3);

  for (int nb = 0; nb < NB; ++nb) {
    const int g = lb * (4 * NB) + nb * 4 + wv;           // wave-group index
    const int P0 = g << 4;                               // first of 16 pixels
    const int b = (P0 >= HW_) ? 1 : 0;
    const int rem = P0 - b * HW_;
    const int i = rem / W_;
    const int j0 = rem - i * W_;     // group never crosses a row (W%16==0)

    f32x4 acc0 = {bias0, bias0, bias0, bias0};
    f32x4 acc1 = {bias1, bias1, bias1, bias1};

    // ---- per-tap: sample 16x32 tile into the k-step slab, MFMA it ----
#pragma unroll
    for (int kk = 0; kk < 9; ++kk) {
      short* buf = slab + (kk & 1) * (16 * SLAB_STRIDE);
      const int di = kk / 3;
      const int dj = kk - di * 3;
#pragma unroll
      for (int s = 0; s < 2; ++s) {
        const int m = s * 8 + q;         // pixel within the 16-tile
        const int j = j0 + m;
        const float2 o = *(const float2*)(off + (((i * W_) + j) * 9 + kk) * 2);
        float yf = (float)(i + di) + o.y;   // padded coords; o.y = y_off
        float xf = (float)(j + dj) + o.x;   // o.x = x_off
        yf = fminf(fmaxf(yf, 0.f), HP1F);
        xf = fminf(fmaxf(xf, 0.f), HP1F);
        const float y0f = floorf(yf);
        const float x0f = floorf(xf);
        const int y0 = (int)y0f;
        const int x0 = (int)x0f;

        float v0, v1, v2, v3;
        // Fast path: all 4 corners strictly inside the image; wave-uniform
        // branch via __all (~94% of iterations, offsets ~N(0,1)).
        const int fast = ((unsigned)(y0 - 1) < 383u) & ((unsigned)(x0 - 1) < 383u);
        if (__all(fast)) {
          const float wy1 = yf - y0f;
          const float wy0 = (y0f + 1.0f) - yf;   // == (float)y1 - yf, y1=y0+1
          const float wx1 = xf - x0f;
          const float wx0 = (x0f + 1.0f) - xf;
          const float w00 = wy0 * wx0, w01 = wy0 * wx1;
          const float w10 = wy1 * wx0, w11 = wy1 * wx1;
          const int base00 = ((b * H_ + (y0 - 1)) * W_ + (x0 - 1)) * C_ + c0;
          // 4 unconditional, independent 16B gathers -> all in flight together
          const float4 p00 = *(const float4*)(x + base00);
          const float4 p01 = *(const float4*)(x + base00 + C_);
          const float4 p10 = *(const float4*)(x + base00 + W_ * C_);
          const float4 p11 = *(const float4*)(x + base00 + W_ * C_ + C_);
          v0 = w00 * p00.x + w01 * p01.x + w10 * p10.x + w11 * p11.x;
          v1 = w00 * p00.y + w01 * p01.y + w10 * p10.y + w11 * p11.y;
          v2 = w00 * p00.z + w01 * p01.z + w10 * p10.z + w11 * p11.z;
          v3 = w00 * p00.w + w01 * p01.w + w10 * p10.w + w11 * p11.w;
        } else {
          // Slow path: verbatim R0 logic (guarded loads, pad corners -> 0).
          const int y1 = min(y0 + 1, 385);
          const int x1 = min(x0 + 1, 385);
          const float wy1 = yf - y0f;
          const float wy0 = (float)y1 - yf;
          const float wx1 = xf - x0f;
          const float wx0 = (float)x1 - xf;
          const float w00 = wy0 * wx0, w01 = wy0 * wx1;
          const float w10 = wy1 * wx0, w11 = wy1 * wx1;

          const int yu0 = y0 - 1, xu0 = x0 - 1;
          const bool vy0 = (unsigned)yu0 < 384u, vy1 = (unsigned)(y1 - 1) < 384u;
          const bool vx0 = (unsigned)xu0 < 384u, vx1 = (unsigned)(x1 - 1) < 384u;
          const int base00 = ((b * H_ + yu0) * W_ + xu0) * C_ + c0;
          const int ddx = (x1 - x0) * C_;
          const int ddy = (y1 - y0) * (W_ * C_);
          float4 p00 = {0.f, 0.f, 0.f, 0.f}, p01 = {0.f, 0.f, 0.f, 0.f};
          float4 p10 = {0.f, 0.f, 0.f, 0.f}, p11 = {0.f, 0.f, 0.f, 0.f};
          if (vy0 && vx0) p00 = *(const float4*)(x + base00);
          if (vy0 && vx1) p01 = *(const float4*)(x + base00 + ddx);
          if (vy1 && vx0) p10 = *(const float4*)(x + base00 + ddy);
          if (vy1 && vx1) p11 = *(const float4*)(x + base00 + ddy + ddx);

          v0 = w00 * p00.x + w01 * p01.x + w10 * p10.x + w11 * p11.x;
          v1 = w00 * p00.y + w01 * p01.y + w10 * p10.y + w11 * p11.y;
          v2 = w00 * p00.z + w01 * p01.z + w10 * p10.z + w11 * p11.z;
          v3 = w00 * p00.w + w01 * p01.w + w10 * p10.w + w11 * p11.w;
        }

        uint2 pw;
        pw.x = f2bf(v0) | ((unsigned)f2bf(v1) << 16);
        pw.y = f2bf(v2) | ((unsigned)f2bf(v3) << 16);
        *(uint2*)&buf[m * SLAB_STRIDE + c0] = pw;
      }
      // wave-private slab: per-wave in-order DS + compiler lgkmcnt ordering;
      // dbuf (kk&1) keeps write(kk) from colliding with in-flight read(kk-1).
      const short8 af = *(const short8*)(buf + mrow * SLAB_STRIDE + qq * 8);
      acc0 = __builtin_amdgcn_mfma_f32_16x16x32_bf16(af, bfrag[0][kk], acc0, 0, 0, 0);
      acc1 = __builtin_amdgcn_mfma_f32_16x16x32_bf16(af, bfrag[1][kk], acc1, 0, 0, 0);
    }

    // D layout: col = lane&15, row = qq*4 + reg
    float* op = out + (size_t)(P0 + qq * 4) * 32 + (lane & 15);
#pragma unroll
    for (int r = 0; r < 4; ++r) {
      op[r * 32] = acc0[r];
      op[r * 32 + 16] = acc1[r];
    }
  }
}

extern "C" void kernel_launch(void* const* d_in, const int* in_sizes, int n_in,
                              void* d_out, int out_size, void* d_ws, size_t ws_size,
                              hipStream_t stream) {
  const float* x    = (const float*)d_in[0];
  const float* off  = (const float*)d_in[1];
  const float* kern = (const float*)d_in[2];
  const float* bias = (const float*)d_in[3];
  float* out = (float*)d_out;
  // 294912 pixels / (4 waves * 16 px * NB batches) = 2304 blocks
  deform_conv_kernel<<<dim3(2304), dim3(256), 0, stream>>>(x, off, kern, bias, out);
}